// Round 17
// baseline (300.277 us; speedup 1.0000x reference)
//
#include <hip/hip_runtime.h>
#include <hip/hip_bf16.h>

#define IN_F 128
#define HF 256
#define BN_EPS 1e-5f
#define SELU_SCALE 1.0507009873554805f
#define SELU_ALPHA 1.6732632423543772f

typedef __attribute__((ext_vector_type(8))) _Float16 half8;
typedef __attribute__((ext_vector_type(2))) unsigned int u32x2;
typedef __attribute__((ext_vector_type(4))) float f32x4;

__device__ __forceinline__ short f2h(float f) {
    _Float16 h = (_Float16)f;               // RTNE fp32->fp16
    return __builtin_bit_cast(short, h);
}

// fast SELU: native v_exp_f32
__device__ __forceinline__ float selu_f(float x) {
    const float SA = SELU_SCALE * SELU_ALPHA;
    float e = __expf(x);
    return x > 0.f ? SELU_SCALE * x : SA * e - SA;
}

// pack 2 fp32 -> 2 fp16 (RTZ), one instruction
__device__ __forceinline__ unsigned int pk2h(float a, float b) {
    return __builtin_bit_cast(unsigned int, __builtin_amdgcn_cvt_pkrtz(a, b));
}

// async global->LDS, 16B/lane; LDS dest MUST be wave-uniform (lane*16 implicit)
__device__ __forceinline__ void gld_lds16(const void* g, void* l) {
    __builtin_amdgcn_global_load_lds(
        (const __attribute__((address_space(1))) unsigned int*)g,
        (__attribute__((address_space(3))) unsigned int*)l, 16, 0, 0);
}

// Fold BN into weights. Layout = fused kernel's per-step (BK=32) B staging:
// Wf[layer][kk(8)][kc(4)][n(256)][j(8)] fp16, k = kk*32 + kc*8 + j.
__global__ void prep_kernel(const float* __restrict__ W0, const float* __restrict__ b0,
                            const float* __restrict__ g0, const float* __restrict__ beta0,
                            const float* __restrict__ m0, const float* __restrict__ v0,
                            const float* __restrict__ Ws, const float* __restrict__ bs,
                            const float* __restrict__ gs, const float* __restrict__ betas,
                            const float* __restrict__ ms, const float* __restrict__ vs,
                            unsigned short* __restrict__ Wf, float* __restrict__ biasArr) {
    int b = blockIdx.x;
    int layer = b >> 8;
    int n = b & 255;
    int k = threadIdx.x;
    const float *W, *bb, *g, *be, *m, *v;
    if (layer == 0) { W = W0; bb = b0; g = g0; be = beta0; m = m0; v = v0; }
    else {
        int i = layer - 1;
        W = Ws + (size_t)i * HF * HF; bb = bs + i * HF; g = gs + i * HF;
        be = betas + i * HF; m = ms + i * HF; v = vs + i * HF;
    }
    float s = g[n] * rsqrtf(v[n] + BN_EPS);
    int kk = k >> 5, kc = (k >> 3) & 3, j = k & 7;
    Wf[((((size_t)layer * 8 + kk) * 4 + kc) * 256 + n) * 8 + j] =
        (unsigned short)f2h(W[n * HF + k] * s);
    if (k == 0) biasArr[layer * HF + n] = (bb[n] - m[n]) * s + be[n];
}

__global__ void count_kernel(const int* __restrict__ dstI, int* __restrict__ cnt, int E) {
    int i = blockIdx.x * 256 + threadIdx.x;
    if (i < E) atomicAdd(cnt + dstI[i], 1);
}

// 3-phase parallel exclusive scan of cnt -> wrk
__global__ void scan_local(const int* __restrict__ cnt, int* __restrict__ wrk,
                           int* __restrict__ btot, int n) {
    __shared__ int s[1024];
    int b = blockIdx.x, t = threadIdx.x, i = b * 1024 + t;
    int v = (i < n) ? cnt[i] : 0;
    s[t] = v;
    __syncthreads();
#pragma unroll
    for (int d = 1; d < 1024; d <<= 1) {
        int add = (t >= d) ? s[t - d] : 0;
        __syncthreads();
        s[t] += add;
        __syncthreads();
    }
    if (i < n) wrk[i] = s[t] - v;
    if (t == 1023) btot[b] = s[1023];
}
__global__ void scan_tops(int* __restrict__ btot, int nb) {
    if (threadIdx.x == 0) {
        int run = 0;
        for (int i = 0; i < nb; ++i) { int v = btot[i]; btot[i] = run; run += v; }
    }
}
__global__ void scan_add(int* __restrict__ wrk, const int* __restrict__ btot, int n) {
    int i = blockIdx.x * 1024 + threadIdx.x;
    if (i < n) wrk[i] += btot[blockIdx.x];
}

// perm[pos] = original edge id, grouped by dst (counting sort)
__global__ void scatter_kernel(const int* __restrict__ dstI, int* __restrict__ wrk,
                               int* __restrict__ perm, int E) {
    int i = blockIdx.x * 256 + threadIdx.x;
    if (i < E) {
        int p = atomicAdd(wrk + dstI[i], 1);
        perm[p] = i;
    }
}

__global__ void finalize_kernel(float* __restrict__ agg, const int* __restrict__ cnt) {
    int n = blockIdx.x;
    float c = fmaxf((float)cnt[n], 1.f);
    agg[(size_t)n * HF + threadIdx.x] = agg[(size_t)n * HF + threadIdx.x] / c;
}

// Fused 3-layer edge MLP over DST-SORTED edges.
// Block = 128 sorted edges x all 256 cols; 512 thr = 8 waves (2 row-halves x
// 4 col-slabs); wave = 64 rows x 64 cols (4x4 frags of mfma_f32_16x16x32_f16).
// DYNAMIC LDS 80KB -> exactly 2 blocks/CU (160KB): A_act 64KB @0 (128 rows x
// 512B fp16, swizzled byte^((row&7)<<4), resident across layers); B 16KB
// @65536 (BK=32, [kc(4)][n(256)][16B]). K-step: {barrier; frag reads; barrier;
// stageB(next) under 16 MFMA}. Layers 1-2 swapped operands -> pkrtz handoff.
// Epilogue: peL/pdL in dead A_act head; 8 rounds of 16 rows via B region;
// h full-row stores to original slots; per-column segment-sum (t<256) -> ~1
// atomic per (dst,col) run.
extern "C" __global__ __launch_bounds__(512, 4)
void fused_kernel(const float* __restrict__ x,
                  const int* __restrict__ dstI, const int* __restrict__ srcI,
                  const int* __restrict__ perm,
                  const unsigned char* __restrict__ Wfb,
                  const float* __restrict__ biasArr,
                  unsigned char* __restrict__ hB, float* __restrict__ agg) {
    extern __shared__ __align__(16) unsigned char lds[];
    unsigned char* ldsB = lds + 65536;

    const int base = blockIdx.x * 128;
    const int t = threadIdx.x;
    const int lane = t & 63;
    const int w = t >> 6;           // 0..7
    const int wr = w >> 2;          // 0..1 : 64-row half
    const int wcol = w & 3;         // 0..3 : 64-col slab
    const int lrow = lane & 15;
    const int lgrp = lane >> 4;

    // stage B(L,kk): 16KB, 2 wave-uniform gld_lds rounds (512 thr x 16B x 2)
    auto stageB = [&](int L, int kk) {
        const unsigned char* src = Wfb + ((size_t)(L * 8 + kk) << 14);
        unsigned char* dstBase = ldsB + w * 1024;
#pragma unroll
        for (int i = 0; i < 2; ++i)
            gld_lds16(src + (i * 512 + t) * 16, dstBase + i * 8192);
    };

    stageB(0, 0);   // prologue stage overlaps the gather below

    // ---- layer-1 A fill: gather x via perm (sorted: dst shared within block) ----
    {
        int r = t >> 2, q = t & 3;                 // sorted row (0..127), col-quarter
        int e = perm[base + r];
        int idx = (q < 2 ? dstI : srcI)[e];
        const float* xr = x + (size_t)idx * IN_F + (q & 1) * 64;
        int swz = (r & 7) << 4;
#pragma unroll
        for (int u = 0; u < 16; ++u) {
            f32x4 v = *(const f32x4*)(xr + u * 4);
            u32x2 hv = {pk2h(v[0], v[1]), pk2h(v[2], v[3])};
            *(u32x2*)&lds[r * 512 + ((q * 128 + u * 8) ^ swz)] = hv;
        }
    }

    f32x4 acc[4][4];
    const f32x4 zero = {0.f, 0.f, 0.f, 0.f};

#pragma unroll
    for (int L = 0; L < 3; ++L) {
#pragma unroll
        for (int mi = 0; mi < 4; ++mi)
#pragma unroll
            for (int ni = 0; ni < 4; ++ni) acc[mi][ni] = zero;

#pragma unroll
        for (int kk = 0; kk < 8; ++kk) {
            __syncthreads();   // B(kk) staged; A_act (gather/handoff) visible

            half8 af[4], bf[4];
#pragma unroll
            for (int mi = 0; mi < 4; ++mi) {
                int row = wr * 64 + mi * 16 + lrow;
                af[mi] = *(const half8*)&lds[row * 512 +
                    ((kk * 64 + lgrp * 16) ^ ((row & 7) << 4))];
            }
#pragma unroll
            for (int ni = 0; ni < 4; ++ni)
                bf[ni] = *(const half8*)&ldsB[lgrp * 4096 +
                                              (wcol * 64 + ni * 16 + lrow) * 16];
            __syncthreads();   // all reads done -> B buffer free

            if (kk < 7) stageB(L, kk + 1);
            else if (L < 2) stageB(L + 1, 0);

            if (L < 2) {
#pragma unroll
                for (int mi = 0; mi < 4; ++mi)
#pragma unroll
                    for (int ni = 0; ni < 4; ++ni)
                        acc[mi][ni] = __builtin_amdgcn_mfma_f32_16x16x32_f16(
                            bf[ni], af[mi], acc[mi][ni], 0, 0, 0);
            } else {
#pragma unroll
                for (int mi = 0; mi < 4; ++mi)
#pragma unroll
                    for (int ni = 0; ni < 4; ++ni)
                        acc[mi][ni] = __builtin_amdgcn_mfma_f32_16x16x32_f16(
                            af[mi], bf[ni], acc[mi][ni], 0, 0, 0);
            }
        }

        if (L < 2) {
            // ---- handoff (swapped layout): lane&15=edge, reg-dim=col ----
#pragma unroll
            for (int ni = 0; ni < 4; ++ni) {
                f32x4 bv = *(const f32x4*)(biasArr + L * HF + wcol * 64 + ni * 16 + lgrp * 4);
#pragma unroll
                for (int mi = 0; mi < 4; ++mi) {
                    int row = wr * 64 + mi * 16 + lrow;
                    float v0 = selu_f(acc[mi][ni][0] + bv[0]);
                    float v1 = selu_f(acc[mi][ni][1] + bv[1]);
                    float v2 = selu_f(acc[mi][ni][2] + bv[2]);
                    float v3 = selu_f(acc[mi][ni][3] + bv[3]);
                    u32x2 d = {pk2h(v0, v1), pk2h(v2, v3)};
                    *(u32x2*)&lds[row * 512 +
                        ((wcol * 128 + ni * 32 + lgrp * 8) ^ ((row & 7) << 4))] = d;
                }
            }
        } else {
            // ---- epilogue: metadata into dead A_act head, then 8 rounds of 16 rows ----
            if (t < 128) {                      // A_act rows 0..1 dead (reads done)
                int e = perm[base + t];
                ((int*)lds)[t] = e;             // peL[128]
                ((int*)lds)[128 + t] = dstI[e]; // pdL[128]
            }
            const int* peL = (const int*)lds;
            const int* pdL = (const int*)lds + 128;
            float bc[4];
#pragma unroll
            for (int ni = 0; ni < 4; ++ni)
                bc[ni] = biasArr[2 * HF + wcol * 64 + ni * 16 + lrow];
            unsigned char* EP = ldsB;
            int curD = -1;
            float carry = 0.f;                  // per-column (t<256) running segment sum
#pragma unroll
            for (int cc = 0; cc < 8; ++cc) {
                if (cc) __syncthreads();
                if (wr == (cc >> 2)) {          // owning half writes rows cc*16..+15
                    int mi = cc & 3;
#pragma unroll
                    for (int ni = 0; ni < 4; ++ni)
#pragma unroll
                        for (int r = 0; r < 4; ++r) {
                            int er = lgrp * 4 + r;             // 0..15
                            int cg = wcol * 64 + ni * 16 + lrow;
                            float val = selu_f(acc[mi][ni][r] + bc[ni]);
                            *(float*)&EP[er * 1024 + ((cg * 4) ^ ((er & 7) << 4))] = val;
                        }
                }
                __syncthreads();                // EP + peL/pdL visible
                // h rows -> original edge slots (full 1KB rows, coalesced)
#pragma unroll
                for (int i = 0; i < 2; ++i) {
                    int f = t + i * 512;                  // 1024 x 16B = 16 rows x 64
                    int row = f >> 6, ch = f & 63;
                    f32x4 v = *(const f32x4*)&EP[row * 1024 + ((ch * 16) ^ ((row & 7) << 4))];
                    *(f32x4*)(hB + (size_t)peL[cc * 16 + row] * 1024 + ch * 16) = v;
                }
                // segment sum: thread t (<256) = column t, walk the 16 sorted rows
                if (t < 256) {
#pragma unroll
                    for (int r = 0; r < 16; ++r) {
                        float v = *(const float*)&EP[r * 1024 + ((t * 4) ^ ((r & 7) << 4))];
                        int d = pdL[cc * 16 + r];
                        if (d != curD) {
                            if (curD >= 0) atomicAdd(agg + (size_t)curD * HF + t, carry);
                            carry = 0.f;
                            curD = d;
                        }
                        carry += v;
                    }
                }
            }
            if (t < 256 && curD >= 0)
                atomicAdd(agg + (size_t)curD * HF + t, carry);   // flush last segment
        }
    }
}

extern "C" void kernel_launch(void* const* d_in, const int* in_sizes, int n_in,
                              void* d_out, int out_size, void* d_ws, size_t ws_size,
                              hipStream_t stream) {
    const float* x     = (const float*)d_in[0];
    const int*   ei    = (const int*)d_in[1];
    const float* W0    = (const float*)d_in[2];
    const float* b0    = (const float*)d_in[3];
    const float* g0    = (const float*)d_in[4];
    const float* beta0 = (const float*)d_in[5];
    const float* m0    = (const float*)d_in[6];
    const float* v0    = (const float*)d_in[7];
    const float* Ws    = (const float*)d_in[8];
    const float* bs    = (const float*)d_in[9];
    const float* gs    = (const float*)d_in[10];
    const float* betas = (const float*)d_in[11];
    const float* ms    = (const float*)d_in[12];
    const float* vs    = (const float*)d_in[13];

    const int Nn = in_sizes[0] / IN_F;   // 20000
    const int E  = in_sizes[1] / 2;      // 320000

    float* agg  = (float*)d_out;
    float* hptr = agg + (size_t)Nn * HF;   // final h region of d_out

    // ws layout (byte offsets): Wf 384KB | bias 3KB | cnt 80KB | wrk 80KB | perm 1.25MB
    char* wsb = (char*)d_ws;
    unsigned short* Wf = (unsigned short*)wsb;                      // 393216 B
    float* biasArr = (float*)(wsb + 393216);                        // 3072 B
    int* cnt  = (int*)(wsb + 396288);                               // 80000 B
    int* wrk  = (int*)(wsb + 476288);                               // 80000 B
    int* perm = (int*)(wsb + 556288);                               // 1280000 B
    int* btot = (int*)agg;            // scratch: agg region, re-zeroed below

    const int* srcI = ei;        // edge_index[0]
    const int* dstI = ei + E;    // edge_index[1]

    const int nScan = (Nn + 1023) / 1024;   // 20
    const int LDS_BYTES = 81920;            // 64KB A_act + 16KB B -> 2 blocks/CU

    hipFuncSetAttribute((const void*)fused_kernel,
                        hipFuncAttributeMaxDynamicSharedMemorySize, LDS_BYTES);

    prep_kernel<<<3 * HF, HF, 0, stream>>>(W0, b0, g0, beta0, m0, v0,
                                           Ws, bs, gs, betas, ms, vs, Wf, biasArr);
    hipMemsetAsync(cnt, 0, (size_t)Nn * sizeof(int), stream);
    count_kernel<<<(E + 255) / 256, 256, 0, stream>>>(dstI, cnt, E);
    scan_local<<<nScan, 1024, 0, stream>>>(cnt, wrk, btot, Nn);
    scan_tops<<<1, 64, 0, stream>>>(btot, nScan);
    scan_add<<<nScan, 1024, 0, stream>>>(wrk, btot, Nn);
    hipMemsetAsync(agg, 0, (size_t)Nn * HF * sizeof(float), stream);  // clears btot too
    scatter_kernel<<<(E + 255) / 256, 256, 0, stream>>>(dstI, wrk, perm, E);

    fused_kernel<<<E / 128, 512, LDS_BYTES, stream>>>(x, dstI, srcI, perm,
                                                      (const unsigned char*)Wf, biasArr,
                                                      (unsigned char*)hptr, agg);

    finalize_kernel<<<Nn, HF, 0, stream>>>(agg, cnt);
}

// Round 18
// 271.673 us; speedup vs baseline: 1.1053x; 1.1053x over previous
//
#include <hip/hip_runtime.h>
#include <hip/hip_bf16.h>

#define IN_F 128
#define HF 256
#define BN_EPS 1e-5f
#define SELU_SCALE 1.0507009873554805f
#define SELU_ALPHA 1.6732632423543772f

typedef __attribute__((ext_vector_type(8))) _Float16 half8;
typedef __attribute__((ext_vector_type(2))) unsigned int u32x2;
typedef __attribute__((ext_vector_type(4))) float f32x4;

__device__ __forceinline__ short f2h(float f) {
    _Float16 h = (_Float16)f;               // RTNE fp32->fp16
    return __builtin_bit_cast(short, h);
}

// fast SELU: native v_exp_f32
__device__ __forceinline__ float selu_f(float x) {
    const float SA = SELU_SCALE * SELU_ALPHA;
    float e = __expf(x);
    return x > 0.f ? SELU_SCALE * x : SA * e - SA;
}

// pack 2 fp32 -> 2 fp16 (RTZ), one instruction
__device__ __forceinline__ unsigned int pk2h(float a, float b) {
    return __builtin_bit_cast(unsigned int, __builtin_amdgcn_cvt_pkrtz(a, b));
}

// async global->LDS, 16B/lane; LDS dest MUST be wave-uniform (lane*16 implicit)
__device__ __forceinline__ void gld_lds16(const void* g, void* l) {
    __builtin_amdgcn_global_load_lds(
        (const __attribute__((address_space(1))) unsigned int*)g,
        (__attribute__((address_space(3))) unsigned int*)l, 16, 0, 0);
}

// Fold BN into weights. Layout = fused kernel's per-step (BK=32) B staging:
// Wf[layer][kk(8)][kc(4)][n(256)][j(8)] fp16, k = kk*32 + kc*8 + j.
__global__ void prep_kernel(const float* __restrict__ W0, const float* __restrict__ b0,
                            const float* __restrict__ g0, const float* __restrict__ beta0,
                            const float* __restrict__ m0, const float* __restrict__ v0,
                            const float* __restrict__ Ws, const float* __restrict__ bs,
                            const float* __restrict__ gs, const float* __restrict__ betas,
                            const float* __restrict__ ms, const float* __restrict__ vs,
                            unsigned short* __restrict__ Wf, float* __restrict__ biasArr) {
    int b = blockIdx.x;
    int layer = b >> 8;
    int n = b & 255;
    int k = threadIdx.x;
    const float *W, *bb, *g, *be, *m, *v;
    if (layer == 0) { W = W0; bb = b0; g = g0; be = beta0; m = m0; v = v0; }
    else {
        int i = layer - 1;
        W = Ws + (size_t)i * HF * HF; bb = bs + i * HF; g = gs + i * HF;
        be = betas + i * HF; m = ms + i * HF; v = vs + i * HF;
    }
    float s = g[n] * rsqrtf(v[n] + BN_EPS);
    int kk = k >> 5, kc = (k >> 3) & 3, j = k & 7;
    Wf[((((size_t)layer * 8 + kk) * 4 + kc) * 256 + n) * 8 + j] =
        (unsigned short)f2h(W[n * HF + k] * s);
    if (k == 0) biasArr[layer * HF + n] = (bb[n] - m[n]) * s + be[n];
}

__global__ void count_kernel(const int* __restrict__ dstI, int* __restrict__ cnt, int E) {
    int i = blockIdx.x * 256 + threadIdx.x;
    if (i < E) atomicAdd(cnt + dstI[i], 1);
}

// 3-phase parallel exclusive scan of cnt -> wrk; ALSO overwrites cnt[i] with
// float 1/max(cnt,1) (the mean divisor, consumed by the fused epilogue).
__global__ void scan_local(int* __restrict__ cnt, int* __restrict__ wrk,
                           int* __restrict__ btot, int n) {
    __shared__ int s[1024];
    int b = blockIdx.x, t = threadIdx.x, i = b * 1024 + t;
    int v = (i < n) ? cnt[i] : 0;
    s[t] = v;
    __syncthreads();
#pragma unroll
    for (int d = 1; d < 1024; d <<= 1) {
        int add = (t >= d) ? s[t - d] : 0;
        __syncthreads();
        s[t] += add;
        __syncthreads();
    }
    if (i < n) {
        wrk[i] = s[t] - v;
        ((float*)cnt)[i] = 1.f / fmaxf((float)v, 1.f);   // inv-count, in place
    }
    if (t == 1023) btot[b] = s[1023];
}
__global__ void scan_tops(int* __restrict__ btot, int nb) {
    if (threadIdx.x == 0) {
        int run = 0;
        for (int i = 0; i < nb; ++i) { int v = btot[i]; btot[i] = run; run += v; }
    }
}
__global__ void scan_add(int* __restrict__ wrk, const int* __restrict__ btot, int n) {
    int i = blockIdx.x * 1024 + threadIdx.x;
    if (i < n) wrk[i] += btot[blockIdx.x];
}

// perm[pos] = original edge id, grouped by dst (counting sort)
__global__ void scatter_kernel(const int* __restrict__ dstI, int* __restrict__ wrk,
                               int* __restrict__ perm, int E) {
    int i = blockIdx.x * 256 + threadIdx.x;
    if (i < E) {
        int p = atomicAdd(wrk + dstI[i], 1);
        perm[p] = i;
    }
}

// Fused 3-layer edge MLP over DST-SORTED edges. Block = 64 sorted edges x all
// 256 cols; 256 thr = 4 waves; wave = 64 rows x its 64-col slab.
// LDS 48KB -> 3 blocks/CU. A_act 32KB @0 (swizzled, resident across layers);
// B single 16KB @32768 (BK=32). K-step: {barrier; read bf (af PREFETCHED -
// A_act is layer-stable, so af reads live in the prior step's MFMA region and
// the barrier-gated window is only 4 bf reads); barrier; stageB(next) + af
// prefetch under 16 MFMA}. Layers 1-2 swapped operands -> pkrtz handoff.
// Epilogue: per 16-row round, stage vals in LDS; h to ORIGINAL edge slot
// (perm) as full 1KB rows; agg = segment-sum over sorted dst runs, flushed
// PRE-SCALED by inv-count -> scatter-MEAN done inline, no finalize kernel.
__global__ __launch_bounds__(256, 3)
void fused_kernel(const float* __restrict__ x,
                  const int* __restrict__ dstI, const int* __restrict__ srcI,
                  const int* __restrict__ perm,
                  const unsigned char* __restrict__ Wfb,
                  const float* __restrict__ biasArr,
                  const float* __restrict__ invA,
                  unsigned char* __restrict__ hB, float* __restrict__ agg) {
    __shared__ __align__(16) unsigned char lds[49152];
    __shared__ int peL[64];   // original edge id per sorted row
    __shared__ int pdL[64];   // dst per sorted row

    const int base = blockIdx.x * 64;
    const int t = threadIdx.x;
    const int lane = t & 63;
    const int w = t >> 6;           // 0..3 : 64-col slab
    const int lrow = lane & 15;
    const int lgrp = lane >> 4;

    // stage B(L,kk): 16KB, 4 wave-uniform gld_lds rounds
    auto stageB = [&](int L, int kk) {
        const unsigned char* src = Wfb + ((size_t)(L * 8 + kk) << 14);
        unsigned char* dstBase = lds + 32768 + w * 1024;
#pragma unroll
        for (int i = 0; i < 4; ++i)
            gld_lds16(src + (i * 256 + t) * 16, dstBase + i * 4096);
    };
    // af fragment read (A_act, swizzled); valid any time A_act is stable
    auto readA = [&](int kk, int mi) -> half8 {
        int row = mi * 16 + lrow;
        return *(const half8*)&lds[row * 512 +
            ((kk * 64 + lgrp * 16) ^ ((row & 7) << 4))];
    };

    stageB(0, 0);   // prologue stage overlaps the gather below

    // ---- layer-1 A fill: gather x via perm (sorted: dst shared within block) ----
    {
        int r = t >> 2, q = t & 3;                 // sorted row, col-quarter
        int e = perm[base + r];
        int idx = (q < 2 ? dstI : srcI)[e];
        const float* xr = x + (size_t)idx * IN_F + (q & 1) * 64;
        int swz = (r & 7) << 4;
#pragma unroll
        for (int u = 0; u < 16; ++u) {
            f32x4 v = *(const f32x4*)(xr + u * 4);
            u32x2 hv = {pk2h(v[0], v[1]), pk2h(v[2], v[3])};
            *(u32x2*)&lds[r * 512 + ((q * 128 + u * 8) ^ swz)] = hv;
        }
    }

    f32x4 acc[4][4];
    const f32x4 zero = {0.f, 0.f, 0.f, 0.f};

#pragma unroll
    for (int L = 0; L < 3; ++L) {
#pragma unroll
        for (int mi = 0; mi < 4; ++mi)
#pragma unroll
            for (int ni = 0; ni < 4; ++ni) acc[mi][ni] = zero;

        half8 af_c[4], af_n[4];
#pragma unroll
        for (int kk = 0; kk < 8; ++kk) {
            __syncthreads();   // B(kk) staged; A_act (gather/handoff) visible

            if (kk == 0) {
#pragma unroll
                for (int mi = 0; mi < 4; ++mi) af_c[mi] = readA(0, mi);
            }
            half8 bf[4];
#pragma unroll
            for (int ni = 0; ni < 4; ++ni)
                bf[ni] = *(const half8*)&lds[32768 + lgrp * 4096 +
                                             (w * 64 + ni * 16 + lrow) * 16];
            __syncthreads();   // bf reads done -> B buffer free

            if (kk < 7) stageB(L, kk + 1);
            else if (L < 2) stageB(L + 1, 0);

            if (kk < 7) {      // prefetch next step's af under the MFMA cluster
#pragma unroll
                for (int mi = 0; mi < 4; ++mi) af_n[mi] = readA(kk + 1, mi);
            }

            if (L < 2) {
#pragma unroll
                for (int mi = 0; mi < 4; ++mi)
#pragma unroll
                    for (int ni = 0; ni < 4; ++ni)
                        acc[mi][ni] = __builtin_amdgcn_mfma_f32_16x16x32_f16(
                            bf[ni], af_c[mi], acc[mi][ni], 0, 0, 0);
            } else {
#pragma unroll
                for (int mi = 0; mi < 4; ++mi)
#pragma unroll
                    for (int ni = 0; ni < 4; ++ni)
                        acc[mi][ni] = __builtin_amdgcn_mfma_f32_16x16x32_f16(
                            af_c[mi], bf[ni], acc[mi][ni], 0, 0, 0);
            }
            if (kk < 7) {
#pragma unroll
                for (int mi = 0; mi < 4; ++mi) af_c[mi] = af_n[mi];
            }
        }

        if (L < 2) {
            // ---- handoff (swapped layout): lane&15=edge, reg-dim=col ----
            // last af read for this layer happened before step 7's barriers.
#pragma unroll
            for (int ni = 0; ni < 4; ++ni) {
                f32x4 bv = *(const f32x4*)(biasArr + L * HF + w * 64 + ni * 16 + lgrp * 4);
#pragma unroll
                for (int mi = 0; mi < 4; ++mi) {
                    int row = mi * 16 + lrow;
                    float v0 = selu_f(acc[mi][ni][0] + bv[0]);
                    float v1 = selu_f(acc[mi][ni][1] + bv[1]);
                    float v2 = selu_f(acc[mi][ni][2] + bv[2]);
                    float v3 = selu_f(acc[mi][ni][3] + bv[3]);
                    u32x2 d = {pk2h(v0, v1), pk2h(v2, v3)};
                    *(u32x2*)&lds[row * 512 +
                        ((w * 128 + ni * 32 + lgrp * 8) ^ ((row & 7) << 4))] = d;
                }
            }
        } else {
            // ---- epilogue: 4 rounds of 16 rows (mi = cc) via 16KB B region ----
            if (t < 64) {                     // sorted-row metadata for this block
                int e = perm[base + t];
                peL[t] = e;
                pdL[t] = dstI[e];
            }
            float bc[4];
#pragma unroll
            for (int ni = 0; ni < 4; ++ni) bc[ni] = biasArr[2 * HF + w * 64 + ni * 16 + lrow];
            unsigned char* EP = lds + 32768;
            int curD = -1;
            float carry = 0.f;                // per-column (t) running segment sum
#pragma unroll
            for (int cc = 0; cc < 4; ++cc) {
                if (cc) __syncthreads();
#pragma unroll
                for (int ni = 0; ni < 4; ++ni)
#pragma unroll
                    for (int r = 0; r < 4; ++r) {
                        int er = lgrp * 4 + r;             // row within round 0..15
                        int cg = w * 64 + ni * 16 + lrow;
                        float val = selu_f(acc[cc][ni][r] + bc[ni]);
                        *(float*)&EP[er * 1024 + ((cg * 4) ^ ((er & 7) << 4))] = val;
                    }
                __syncthreads();              // EP + peL/pdL visible
                // h rows -> original edge slots (full 1KB rows, coalesced)
#pragma unroll
                for (int i = 0; i < 4; ++i) {
                    int f = t + i * 256;                  // 1024 x 16B = 16 rows x 64
                    int row = f >> 6, ch = f & 63;
                    f32x4 v = *(const f32x4*)&EP[row * 1024 + ((ch * 16) ^ ((row & 7) << 4))];
                    *(f32x4*)(hB + (size_t)peL[cc * 16 + row] * 1024 + ch * 16) = v;
                }
                // segment sum: thread t = column t, walk the 16 sorted rows
#pragma unroll
                for (int r = 0; r < 16; ++r) {
                    float v = *(const float*)&EP[r * 1024 + ((t * 4) ^ ((r & 7) << 4))];
                    int d = pdL[cc * 16 + r];
                    if (d != curD) {
                        if (curD >= 0)
                            atomicAdd(agg + (size_t)curD * HF + t, carry * invA[curD]);
                        carry = 0.f;
                        curD = d;
                    }
                    carry += v;
                }
            }
            atomicAdd(agg + (size_t)curD * HF + t, carry * invA[curD]);  // flush last
        }
    }
}

extern "C" void kernel_launch(void* const* d_in, const int* in_sizes, int n_in,
                              void* d_out, int out_size, void* d_ws, size_t ws_size,
                              hipStream_t stream) {
    const float* x     = (const float*)d_in[0];
    const int*   ei    = (const int*)d_in[1];
    const float* W0    = (const float*)d_in[2];
    const float* b0    = (const float*)d_in[3];
    const float* g0    = (const float*)d_in[4];
    const float* beta0 = (const float*)d_in[5];
    const float* m0    = (const float*)d_in[6];
    const float* v0    = (const float*)d_in[7];
    const float* Ws    = (const float*)d_in[8];
    const float* bs    = (const float*)d_in[9];
    const float* gs    = (const float*)d_in[10];
    const float* betas = (const float*)d_in[11];
    const float* ms    = (const float*)d_in[12];
    const float* vs    = (const float*)d_in[13];

    const int Nn = in_sizes[0] / IN_F;   // 20000
    const int E  = in_sizes[1] / 2;      // 320000

    float* agg  = (float*)d_out;
    float* hptr = agg + (size_t)Nn * HF;   // final h region of d_out

    // ws layout (byte offsets): Wf 384KB | bias 3KB | cnt/inv 80KB | wrk 80KB | perm 1.25MB
    char* wsb = (char*)d_ws;
    unsigned short* Wf = (unsigned short*)wsb;                      // 393216 B
    float* biasArr = (float*)(wsb + 393216);                        // 3072 B
    int* cnt  = (int*)(wsb + 396288);                               // 80000 B (becomes inv f32)
    int* wrk  = (int*)(wsb + 476288);                               // 80000 B
    int* perm = (int*)(wsb + 556288);                               // 1280000 B
    int* btot = (int*)agg;            // scratch: agg region, re-zeroed below

    const int* srcI = ei;        // edge_index[0]
    const int* dstI = ei + E;    // edge_index[1]

    const int nScan = (Nn + 1023) / 1024;   // 20

    prep_kernel<<<3 * HF, HF, 0, stream>>>(W0, b0, g0, beta0, m0, v0,
                                           Ws, bs, gs, betas, ms, vs, Wf, biasArr);
    hipMemsetAsync(cnt, 0, (size_t)Nn * sizeof(int), stream);
    count_kernel<<<(E + 255) / 256, 256, 0, stream>>>(dstI, cnt, E);
    scan_local<<<nScan, 1024, 0, stream>>>(cnt, wrk, btot, Nn);   // also cnt -> inv
    scan_tops<<<1, 64, 0, stream>>>(btot, nScan);
    scan_add<<<nScan, 1024, 0, stream>>>(wrk, btot, Nn);
    hipMemsetAsync(agg, 0, (size_t)Nn * HF * sizeof(float), stream);  // clears btot too
    scatter_kernel<<<(E + 255) / 256, 256, 0, stream>>>(dstI, wrk, perm, E);

    fused_kernel<<<E / 64, 256, 0, stream>>>(x, dstI, srcI, perm,
                                             (const unsigned char*)Wf, biasArr,
                                             (const float*)cnt,
                                             (unsigned char*)hptr, agg);
}